// Round 3
// baseline (62.895 us; speedup 1.0000x reference)
//
#include <hip/hip_runtime.h>

// out[i, 7n+o, m] = sum_{j,k} x[j, 7n+o+k-1, m] * W[i,j,k], taps clipped to o+k-1 in [0,7)
// x: (48,56,56) f32, W: (192,48,3) f32, out: (192,56,56) f32
//
// R10: barrier-free split-K. Block = 256 thr = 8 cols x 8 j-segs (one wave)
// x 4 rowgroups (one per wave: o={0,1},{2,3},{4,5},{6}). Split-K reduction is a
// 3-step in-wave __shfl_xor butterfly over the seg lane bits -> no reduction
// LDS (32KB -> 3KB), no barriers after W staging. acc[4][2] = 32 VGPR; ~105
// VGPR total with unroll 2 -> 4 blocks/CU, all 672 blocks co-resident.

#define CH_IN 48
#define CH_OUT 192
#define HW 56
#define SP 3136   // 56*56
#define OB 7
#define M4 14
#define SEGS 8
#define JSEG 6    // 48/8
#define BCOL 8
#define IG 4
#define CG 14     // colgroups per channel (112/8)
#define WST 144   // 48*3 floats per W row

__device__ __forceinline__ void fma4(float4& a, float s, const float4& b) {
    a.x += s * b.x; a.y += s * b.y; a.z += s * b.z; a.w += s * b.w;
}
__device__ __forceinline__ void red_xor(float4& a, int mask) {
    a.x += __shfl_xor(a.x, mask, 64);
    a.y += __shfl_xor(a.y, mask, 64);
    a.z += __shfl_xor(a.z, mask, 64);
    a.w += __shfl_xor(a.w, mask, 64);
}

__global__ __launch_bounds__(256, 4) void conv_bf_kernel(const float* __restrict__ x,
                                                         const float* __restrict__ W,
                                                         float* __restrict__ out) {
    __shared__ float4 wlds[IG][CH_IN];   // 3 KB: (w0,w1,w2,pad) per (ig, j)

    const int tid = threadIdx.x;
    const int c   = tid & (BCOL - 1);        // column [0,8)
    const int seg = (tid >> 3) & (SEGS - 1); // j-segment [0,8)  (in-wave)
    const int rg  = tid >> 6;                // wave index [0,4) (uniform)
    const int ig4 = blockIdx.x / CG;
    const int cg  = blockIdx.x % CG;
    const int i0  = ig4 * IG;

    // Stage the 4-channel W slice (576 contiguous floats) into padded LDS.
    {
        const float* wsrc = W + i0 * WST;
        float* wf = reinterpret_cast<float*>(&wlds[0][0]);
        for (int f = tid; f < IG * WST; f += 256) {
            const int jg = f / 3;            // ig*48 + j  in [0,192)
            const int k  = f - jg * 3;
            wf[jg * 4 + k] = wsrc[f];
        }
    }

    const int col = cg * BCOL + c;           // [0,112)
    const int n   = col / M4;
    const int m4  = col - n * M4;

    const float* xcol = x + seg * (JSEG * SP) + n * (OB * HW) + m4 * 4;
    const int wj0 = seg * JSEG;

    float4 acc[IG][2];
#pragma unroll
    for (int ig = 0; ig < IG; ++ig) {
        acc[ig][0] = make_float4(0.f, 0.f, 0.f, 0.f);
        acc[ig][1] = make_float4(0.f, 0.f, 0.f, 0.f);
    }

    __syncthreads();   // wlds ready (only barrier in the kernel)

    if (rg == 0) {
        // o=0 (w1*r0 + w2*r1; k=0 tap is zero-pad), o=1 (rows 0..2)
#pragma unroll 2
        for (int j = 0; j < JSEG; ++j) {
            const float* xj = xcol + j * SP;
            const float4 r0 = *reinterpret_cast<const float4*>(xj + 0 * HW);
            const float4 r1 = *reinterpret_cast<const float4*>(xj + 1 * HW);
            const float4 r2 = *reinterpret_cast<const float4*>(xj + 2 * HW);
#pragma unroll
            for (int ig = 0; ig < IG; ++ig) {
                const float4 w = wlds[ig][wj0 + j];
                fma4(acc[ig][0], w.y, r0);
                fma4(acc[ig][0], w.z, r1);
                fma4(acc[ig][1], w.x, r0);
                fma4(acc[ig][1], w.y, r1);
                fma4(acc[ig][1], w.z, r2);
            }
        }
    } else if (rg == 1) {
        // o=2 (rows 1..3), o=3 (rows 2..4)
#pragma unroll 2
        for (int j = 0; j < JSEG; ++j) {
            const float* xj = xcol + j * SP;
            const float4 r1 = *reinterpret_cast<const float4*>(xj + 1 * HW);
            const float4 r2 = *reinterpret_cast<const float4*>(xj + 2 * HW);
            const float4 r3 = *reinterpret_cast<const float4*>(xj + 3 * HW);
            const float4 r4 = *reinterpret_cast<const float4*>(xj + 4 * HW);
#pragma unroll
            for (int ig = 0; ig < IG; ++ig) {
                const float4 w = wlds[ig][wj0 + j];
                fma4(acc[ig][0], w.x, r1);
                fma4(acc[ig][0], w.y, r2);
                fma4(acc[ig][0], w.z, r3);
                fma4(acc[ig][1], w.x, r2);
                fma4(acc[ig][1], w.y, r3);
                fma4(acc[ig][1], w.z, r4);
            }
        }
    } else if (rg == 2) {
        // o=4 (rows 3..5), o=5 (rows 4..6)
#pragma unroll 2
        for (int j = 0; j < JSEG; ++j) {
            const float* xj = xcol + j * SP;
            const float4 r3 = *reinterpret_cast<const float4*>(xj + 3 * HW);
            const float4 r4 = *reinterpret_cast<const float4*>(xj + 4 * HW);
            const float4 r5 = *reinterpret_cast<const float4*>(xj + 5 * HW);
            const float4 r6 = *reinterpret_cast<const float4*>(xj + 6 * HW);
#pragma unroll
            for (int ig = 0; ig < IG; ++ig) {
                const float4 w = wlds[ig][wj0 + j];
                fma4(acc[ig][0], w.x, r3);
                fma4(acc[ig][0], w.y, r4);
                fma4(acc[ig][0], w.z, r5);
                fma4(acc[ig][1], w.x, r4);
                fma4(acc[ig][1], w.y, r5);
                fma4(acc[ig][1], w.z, r6);
            }
        }
    } else {
        // o=6 (w0*r5 + w1*r6; k=2 tap is zero-pad)
#pragma unroll 2
        for (int j = 0; j < JSEG; ++j) {
            const float* xj = xcol + j * SP;
            const float4 r5 = *reinterpret_cast<const float4*>(xj + 5 * HW);
            const float4 r6 = *reinterpret_cast<const float4*>(xj + 6 * HW);
#pragma unroll
            for (int ig = 0; ig < IG; ++ig) {
                const float4 w = wlds[ig][wj0 + j];
                fma4(acc[ig][0], w.x, r5);
                fma4(acc[ig][0], w.y, r6);
            }
        }
    }

    // In-wave butterfly reduction over the 8 j-segments (lane bits 3..5).
#pragma unroll
    for (int ig = 0; ig < IG; ++ig) {
        red_xor(acc[ig][0], 8);
        red_xor(acc[ig][0], 16);
        red_xor(acc[ig][0], 32);
        if (rg < 3) {           // wave-uniform; rg3 has no second output row
            red_xor(acc[ig][1], 8);
            red_xor(acc[ig][1], 16);
            red_xor(acc[ig][1], 32);
        }
    }

    if (seg == 0) {
        float* op = out + n * (OB * HW) + (rg * 2) * HW + m4 * 4;
#pragma unroll
        for (int ig = 0; ig < IG; ++ig) {
            float* oi = op + (i0 + ig) * SP;
            *reinterpret_cast<float4*>(oi) = acc[ig][0];
            if (rg < 3)
                *reinterpret_cast<float4*>(oi + HW) = acc[ig][1];
        }
    }
}

extern "C" void kernel_launch(void* const* d_in, const int* in_sizes, int n_in,
                              void* d_out, int out_size, void* d_ws, size_t ws_size,
                              hipStream_t stream) {
    const float* x = (const float*)d_in[0];
    const float* W = (const float*)d_in[1];
    float* out = (float*)d_out;

    const int grid = (CH_OUT / IG) * CG;  // 672 blocks x 256 threads
    conv_bf_kernel<<<grid, 256, 0, stream>>>(x, W, out);
}